// Round 14
// baseline (78.936 us; speedup 1.0000x reference)
//
#include <hip/hip_runtime.h>
#include <hip/hip_bf16.h>
#include <cstdint>
#include <cstddef>

// Problem constants
#define NROWS 4096
#define DIMK  640
// reg = 1/LAMBDA = 10;  K = exp(-D/reg) = exp(0.2*S - 0.2), S = cosine sim
// K in [exp(-0.4), 1] -> affine uint8 quantization K ~= QA*q + QB
#define QB 0.67032004603564f           /* exp(-0.4) */
#define QA 0.0012928625645661f         /* (1 - exp(-0.4)) / 255 */
// Sinkhorn closed form (verified R8-R13): W = c0*v1_i*v1_j*K_ij, diag=1,
// c0 = 1/sum(v1).  Analytic v1 (verified R11-R13):
//   v1_i = N*e^{0.2} / (C0 + 0.2*t_i),  t_i = v_i . s,  s = V^T 1,
//   C0 = N + 0.02 + 0.02*(N-1)/DIMK - e^{0.2}
#define EXP02 1.2214027581601699f
#define RS_C0 4094.9265661f
#define FIXS  65536.0f
#define FIXSI (1.0f / 65536.0f)

typedef __bf16 bf16_t;
typedef __bf16 bf16x8 __attribute__((ext_vector_type(8)));
typedef float  f32x4  __attribute__((ext_vector_type(4)));

// ---------------------------------------------------------------------------
// A: row-normalize x -> bf16 V + deterministic fixed-point column sums.
// (verified R12/R13)
// ---------------------------------------------------------------------------
__global__ __launch_bounds__(256)
void rownorm_colsum_kernel(const float* __restrict__ x, bf16_t* __restrict__ Vb,
                           int* __restrict__ s_int) {
    __shared__ float P[4][DIMK];
    const int t = threadIdx.x, lane = t & 63, w = t >> 6;
    const int row = blockIdx.x * 4 + w;
    const float* xr = x + (size_t)row * DIMK;
    float xv[10], ss = 0.f;
#pragma unroll
    for (int i = 0; i < 10; ++i) { xv[i] = xr[lane + i * 64]; ss += xv[i] * xv[i]; }
#pragma unroll
    for (int off = 32; off > 0; off >>= 1) ss += __shfl_xor(ss, off, 64);
    const float inv = 1.0f / sqrtf(ss);
    bf16_t* vr = Vb + (size_t)row * DIMK;
#pragma unroll
    for (int i = 0; i < 10; ++i) {
        const float f = xv[i] * inv;
        vr[lane + i * 64] = (bf16_t)f;
        P[w][lane + i * 64] = f;
    }
    __syncthreads();
    for (int k = t; k < DIMK; k += 256)
        atomicAdd(s_int + k,
                  (int)rintf((P[0][k] + P[1][k] + P[2][k] + P[3][k]) * FIXS));
}

// ---------------------------------------------------------------------------
// C: v1_i = N*e^{0.2} / (C0 + 0.2 * (v_i . s)).   (verified R12/R13)
// ---------------------------------------------------------------------------
__global__ __launch_bounds__(256)
void v1_kernel(const bf16_t* __restrict__ Vb, const int* __restrict__ s_int,
               float* __restrict__ v1) {
    const int t = threadIdx.x, lane = t & 63, w = t >> 6;
    const int row = blockIdx.x * 4 + w;
    const uint32_t* vr = (const uint32_t*)(Vb + (size_t)row * DIMK);
    const int2* s2 = (const int2*)s_int;
    float dot = 0.f;
#pragma unroll
    for (int i = 0; i < 5; ++i) {
        const int d = lane + i * 64;
        const uint32_t u = vr[d];
        const int2 sp = s2[d];
        const float f0 = __builtin_bit_cast(float, u << 16);
        const float f1 = __builtin_bit_cast(float, u & 0xffff0000u);
        dot = fmaf(f0, (float)sp.x * FIXSI, dot);
        dot = fmaf(f1, (float)sp.y * FIXSI, dot);
    }
#pragma unroll
    for (int off = 32; off > 0; off >>= 1) dot += __shfl_xor(dot, off, 64);
    if (lane == 0)
        v1[row] = ((float)NROWS * EXP02) / fmaf(0.2f, dot, RS_C0);
}

// ---------------------------------------------------------------------------
// helper: async global->LDS, 16B per lane
// ---------------------------------------------------------------------------
__device__ __forceinline__ void gload_lds16(const bf16_t* g, bf16_t* l) {
    __builtin_amdgcn_global_load_lds(
        (const __attribute__((address_space(1))) void*)g,
        (__attribute__((address_space(3))) void*)l,
        16, 0, 0);
}

// ---------------------------------------------------------------------------
// D: symmetric K-GEMM -> u8.  R14: FULL 128x128 tiles (528 blocks) to cut
// redundant V reads 259->173 MB (the real binder, see R13 post-mortem).
// BK=32, TRIPLE-buffered LDS (3 x 16KB = 48KB -> 3 blocks/CU; all 528
// co-resident, single round).  T4 counted vmcnt: prefetch distance 2,
// vmcnt(4) per step (4 gloads/thread/stage), loads fly across barriers;
// only kt=18 drains.  m204 XCD-chunked swizzle (528 = 8*66): same-by tiles
// share an XCD -> A panels L2-hot.  Epilogue = R9's proven dual-orientation
// u8 writes (no rowsum atomics; v1 is analytic).
// ---------------------------------------------------------------------------
__global__ __launch_bounds__(256, 3)
void gemm_ku8_kernel(const bf16_t* __restrict__ Vb, unsigned char* __restrict__ Kq) {
    // 3 buffers x (A 4096 | B 4096) bf16 elems = 48 KB
    __shared__ __align__(16) bf16_t SMEM[3 * 8192];

    const int t    = threadIdx.x;
    const int lane = t & 63;
    const int wid  = t >> 6;
    const int wr   = wid >> 1;
    const int wc   = wid & 1;
    const int lane15 = lane & 15;
    const int lhi    = lane >> 4;

    // XCD-chunked bijective swizzle (m204; 528 = 8*66, r=0)
    int lid = (blockIdx.x & 7) * 66 + (blockIdx.x >> 3);
    int by = 0;
    while (lid >= 32 - by) { lid -= 32 - by; ++by; }
    const int bx = by + lid;
    const int rowA0 = by * 128;
    const int rowB0 = bx * 128;

    f32x4 acc[4][4];
#pragma unroll
    for (int i = 0; i < 4; ++i)
#pragma unroll
        for (int j = 0; j < 4; ++j) acc[i][j] = (f32x4){0.f, 0.f, 0.f, 0.f};

    // stage one BK=32 tile-pair into buffer `bptr`: 4 gloads/thread
    // chunk swizzle: global chunk c stored at LDS slot c ^ (r&3)
#define STAGE_KT(bptr, kt)                                                         \
    {                                                                              \
        bf16_t* Abuf = (bptr);                                                     \
        bf16_t* Bbuf = (bptr) + 4096;                                              \
        _Pragma("unroll")                                                          \
        for (int it = 0; it < 2; ++it) {   /* A: 128 rows x 4 chunks = 512 */      \
            const int s = it * 256 + t;                                            \
            const int r = s >> 2;                                                  \
            const int c = (s & 3) ^ (r & 3);                                       \
            gload_lds16(Vb + (size_t)(rowA0 + r) * DIMK + (kt) * 32 + c * 8,       \
                        Abuf + s * 8);                                             \
        }                                                                          \
        _Pragma("unroll")                                                          \
        for (int it = 0; it < 2; ++it) {   /* B: 128 rows x 4 chunks = 512 */      \
            const int s = it * 256 + t;                                            \
            const int r = s >> 2;                                                  \
            const int c = (s & 3) ^ (r & 3);                                       \
            gload_lds16(Vb + (size_t)(rowB0 + r) * DIMK + (kt) * 32 + c * 8,       \
                        Bbuf + s * 8);                                             \
        }                                                                          \
    }

    // prologue: prefetch kt=0 and kt=1; wait only for kt=0 (oldest 4)
    STAGE_KT(SMEM, 0);
    STAGE_KT(SMEM + 8192, 1);
    asm volatile("s_waitcnt vmcnt(4)" ::: "memory");
    __builtin_amdgcn_s_barrier();
    __builtin_amdgcn_sched_barrier(0);

    for (int kt = 0; kt < 20; ++kt) {
        if (kt < 18) {
            bf16_t* nb = SMEM + (size_t)((kt + 2) % 3) * 8192;
            STAGE_KT(nb, kt + 2);
        }

        const bf16_t* Ac = SMEM + (size_t)(kt % 3) * 8192;
        const bf16_t* Bc = Ac + 4096;
        bf16x8 af[4], bfr[4];
#pragma unroll
        for (int mi = 0; mi < 4; ++mi) {
            const int rl = wr * 64 + mi * 16 + lane15;       // 0..127
            af[mi] = *(const bf16x8*)(Ac + rl * 32 + ((lhi ^ (rl & 3)) * 8));
        }
#pragma unroll
        for (int ni = 0; ni < 4; ++ni) {
            const int cl = wc * 64 + ni * 16 + lane15;       // 0..127
            bfr[ni] = *(const bf16x8*)(Bc + cl * 32 + ((lhi ^ (cl & 3)) * 8));
        }
#pragma unroll
        for (int mi = 0; mi < 4; ++mi)
#pragma unroll
            for (int ni = 0; ni < 4; ++ni)
                acc[mi][ni] = __builtin_amdgcn_mfma_f32_16x16x32_bf16(
                    af[mi], bfr[ni], acc[mi][ni], 0, 0, 0);

        // counted wait: kt+1's stage (oldest 4) must be done; kt+2's may fly.
        if (kt < 18) {
            asm volatile("s_waitcnt vmcnt(4)" ::: "memory");
        } else if (kt == 18) {
            asm volatile("s_waitcnt vmcnt(0)" ::: "memory");
        }
        __builtin_amdgcn_s_barrier();
        __builtin_amdgcn_sched_barrier(0);
    }
#undef STAGE_KT

    // ---- epilogue (R9-proven, minus rowsum atomics): quantize to u8, stage
    // transposed Tt[c][r] in LDS (dword-swizzled), dual-orientation writes.
    unsigned char* Tt = (unsigned char*)SMEM;
    uint32_t* Tt32 = (uint32_t*)Tt;
    __syncthreads();
#pragma unroll
    for (int mi = 0; mi < 4; ++mi) {
#pragma unroll
        for (int ni = 0; ni < 4; ++ni) {
            const int lr0 = wr * 64 + mi * 16 + lhi * 4;
            const int lc  = wc * 64 + ni * 16 + lane15;
            uint32_t pack = 0;
#pragma unroll
            for (int j = 0; j < 4; ++j) {
                const float s = acc[mi][ni][j];
                float kv = __expf(0.2f * s - 0.2f);
                int q = (int)rintf((kv - QB) / QA);
                q = q < 0 ? 0 : (q > 255 ? 255 : q);
                if (rowA0 + lr0 + j == rowB0 + lc) q = 0;
                pack |= (uint32_t)q << (8 * j);
            }
            const int d = lr0 >> 2;
            Tt32[lc * 32 + (d ^ (lc & 7))] = pack;
        }
    }
    __syncthreads();

    // orientation 1 (always): K[rowB0+c][rowA0 + half*64 ..]
    {
        const int c    = t >> 1;
        const int half = t & 1;
        uint32_t w[16];
#pragma unroll
        for (int k = 0; k < 16; ++k) {
            const int d = half * 16 + k;
            w[k] = Tt32[c * 32 + (d ^ (c & 7))];
        }
        uint32_t* dst = (uint32_t*)(Kq + (size_t)(rowB0 + c) * NROWS + rowA0 + half * 64);
#pragma unroll
        for (int k = 0; k < 4; ++k)
            ((uint4*)dst)[k] = make_uint4(w[4 * k], w[4 * k + 1], w[4 * k + 2], w[4 * k + 3]);
    }

    // orientation 2 (off-diag only): K[rowA0+r][rowB0 + half*64 ..]
    if (bx != by) {
        const int r    = t >> 1;
        const int half = t & 1;
        uint32_t* dst = (uint32_t*)(Kq + (size_t)(rowA0 + r) * NROWS + rowB0 + half * 64);
        const int rd = r >> 2, rb = r & 3;
#pragma unroll
        for (int k = 0; k < 16; ++k) {
            uint32_t pack = 0;
#pragma unroll
            for (int b = 0; b < 4; ++b) {
                const int c = half * 64 + k * 4 + b;
                pack |= (uint32_t)Tt[c * 128 + ((rd ^ (c & 7)) << 2) + rb] << (8 * b);
            }
            dst[k] = pack;
        }
    }
}

// ---------------------------------------------------------------------------
// E: closed-form final W (verified R13):
//   c0 = 1/sum(v1);  W[i][j] = (c0*v1[i]) * (QA*q[i][j] + QB) * v1[j]; diag=1
// ---------------------------------------------------------------------------
__global__ __launch_bounds__(256)
void finalw_closed_kernel(const unsigned char* __restrict__ Kq,
                          const float* __restrict__ v1,
                          float* __restrict__ W) {
    __shared__ float xs[NROWS];
    __shared__ float sxp[4];
    const int t    = threadIdx.x;
    const int lane = t & 63;
    const int w    = t >> 6;

    float psum = 0.f;
    float4* xs4 = (float4*)xs;
    const float4* v4 = (const float4*)v1;
#pragma unroll
    for (int i = 0; i < 4; ++i) {
        const float4 vv = v4[i * 256 + t];
        xs4[i * 256 + t] = vv;
        psum += vv.x + vv.y + vv.z + vv.w;
    }
#pragma unroll
    for (int off = 32; off > 0; off >>= 1) psum += __shfl_xor(psum, off, 64);
    if (lane == 0) sxp[w] = psum;
    __syncthreads();
    const float c0 = 1.0f / (sxp[0] + sxp[1] + sxp[2] + sxp[3]);

#pragma unroll
    for (int r = 0; r < 4; ++r) {
        const int grow = blockIdx.x * 4 + r;
        const float ui   = c0 * xs[grow];
        const float qa_u = QA * ui;
        const float qb_u = QB * ui;
        const uint32_t* Krow = (const uint32_t*)(Kq + (size_t)grow * NROWS);
        f32x4* Wrow = (f32x4*)(W + (size_t)grow * NROWS);
#pragma unroll
        for (int i = 0; i < 4; ++i) {
            const int idx = i * 256 + t;
            const uint32_t q = Krow[idx];
            const float4 vv = ((const float4*)xs4)[idx];
            f32x4 wv;
            wv[0] = fmaf(qa_u, (float)(q & 255u),         qb_u) * vv.x;
            wv[1] = fmaf(qa_u, (float)((q >> 8) & 255u),  qb_u) * vv.y;
            wv[2] = fmaf(qa_u, (float)((q >> 16) & 255u), qb_u) * vv.z;
            wv[3] = fmaf(qa_u, (float)(q >> 24),          qb_u) * vv.w;
            const int d = grow - idx * 4;
            if (d == 0) wv[0] = 1.0f;
            if (d == 1) wv[1] = 1.0f;
            if (d == 2) wv[2] = 1.0f;
            if (d == 3) wv[3] = 1.0f;
            __builtin_nontemporal_store(wv, Wrow + idx);
        }
    }
}

// ---------------------------------------------------------------------------
// f32 fallback path (only if ws too small — never expected): R5 semantics.
// ---------------------------------------------------------------------------
__global__ void init_u_kernel(float* __restrict__ u) {
    const int i = blockIdx.x * 256 + threadIdx.x;
    if (i < NROWS) u[i] = 1.0f / (float)NROWS;
}

__global__ __launch_bounds__(256)
void gemm_k_f32_kernel(const bf16_t* __restrict__ Vb, float* __restrict__ Kout) {
    __shared__ __align__(16) bf16_t As[128 * 64];
    __shared__ __align__(16) bf16_t Bs[128 * 64];
    const int t = threadIdx.x, lane = t & 63, wid = t >> 6;
    const int wr = wid >> 1, wc = wid & 1;
    const int rowA0 = blockIdx.y * 128, rowB0 = blockIdx.x * 128;
    f32x4 acc[4][4];
#pragma unroll
    for (int i = 0; i < 4; ++i)
#pragma unroll
        for (int j = 0; j < 4; ++j) acc[i][j] = (f32x4){0.f, 0.f, 0.f, 0.f};
    for (int kt = 0; kt < DIMK / 64; ++kt) {
#pragma unroll
        for (int it = 0; it < 4; ++it) {
            const int s = it * 256 + t;
            const int r = s >> 3;
            const int c = (s & 7) ^ (r & 7);
            gload_lds16(Vb + (size_t)(rowA0 + r) * DIMK + kt * 64 + c * 8, As + s * 8);
            gload_lds16(Vb + (size_t)(rowB0 + r) * DIMK + kt * 64 + c * 8, Bs + s * 8);
        }
        __syncthreads();
#pragma unroll
        for (int kk = 0; kk < 2; ++kk) {
            bf16x8 af[4], bfr[4];
#pragma unroll
            for (int mi = 0; mi < 4; ++mi) {
                const int rl = wr * 64 + mi * 16 + (lane & 15);
                const int cs = kk * 4 + (lane >> 4);
                af[mi] = *(const bf16x8*)(As + rl * 64 + ((cs ^ (rl & 7)) * 8));
                const int cl = wc * 64 + mi * 16 + (lane & 15);
                bfr[mi] = *(const bf16x8*)(Bs + cl * 64 + ((cs ^ (cl & 7)) * 8));
            }
#pragma unroll
            for (int mi = 0; mi < 4; ++mi)
#pragma unroll
                for (int ni = 0; ni < 4; ++ni)
                    acc[mi][ni] = __builtin_amdgcn_mfma_f32_16x16x32_bf16(
                        af[mi], bfr[ni], acc[mi][ni], 0, 0, 0);
        }
        __syncthreads();
    }
#pragma unroll
    for (int mi = 0; mi < 4; ++mi)
#pragma unroll
        for (int ni = 0; ni < 4; ++ni)
#pragma unroll
            for (int j = 0; j < 4; ++j) {
                const int grow = rowA0 + wr * 64 + mi * 16 + (lane >> 4) * 4 + j;
                const int gcol = rowB0 + wc * 64 + ni * 16 + (lane & 15);
                float kv = __expf(0.2f * acc[mi][ni][j] - 0.2f);
                if (grow == gcol) kv = 0.0f;
                Kout[(size_t)grow * NROWS + gcol] = kv;
            }
}

__global__ void matvec_f32_kernel(const float* __restrict__ K,
                                  const float* __restrict__ x,
                                  float* __restrict__ y) {
    const int row = blockIdx.x, t = threadIdx.x;
    const float4* Kr = (const float4*)(K + (size_t)row * NROWS);
    const float4* xv = (const float4*)x;
    float s = 0.f;
#pragma unroll
    for (int i = 0; i < 4; ++i) {
        const int idx = i * 256 + t;
        const float4 kv = Kr[idx];
        const float4 xw = xv[idx];
        s += kv.x * xw.x + kv.y * xw.y + kv.z * xw.z + kv.w * xw.w;
    }
    for (int off = 32; off > 0; off >>= 1) s += __shfl_down(s, off, 64);
    __shared__ float p[4];
    const int lane = t & 63, wid = t >> 6;
    if (lane == 0) p[wid] = s;
    __syncthreads();
    if (t == 0) y[row] = 1.0f / (p[0] + p[1] + p[2] + p[3]);
}

__global__ void finalw_f32_kernel(float* __restrict__ W,
                                  const float* __restrict__ u,
                                  const float* __restrict__ v) {
    const size_t idx = (size_t)blockIdx.x * 256 + threadIdx.x;
    const size_t base = idx * 4;
    const int i = (int)(base >> 12), j0 = (int)(base & 4095);
    const float ui = u[i];
    float4 kv = ((const float4*)W)[idx];
    const float4 vv = *(const float4*)(v + j0);
    float4 w;
    w.x = ui * kv.x * vv.x;
    w.y = ui * kv.y * vv.y;
    w.z = ui * kv.z * vv.z;
    w.w = ui * kv.w * vv.w;
    const int d = i - j0;
    if (d == 0) w.x = 1.0f;
    if (d == 1) w.y = 1.0f;
    if (d == 2) w.z = 1.0f;
    if (d == 3) w.w = 1.0f;
    ((float4*)W)[idx] = w;
}

// ---------------------------------------------------------------------------
extern "C" void kernel_launch(void* const* d_in, const int* in_sizes, int n_in,
                              void* d_out, int out_size, void* d_ws, size_t ws_size,
                              hipStream_t stream) {
    const float* x = (const float*)d_in[0];
    float* W = (float*)d_out;
    char* ws = (char*)d_ws;

    size_t off = 0;
    bf16_t* Vb = (bf16_t*)(ws + off); off += (size_t)NROWS * DIMK * sizeof(bf16_t);
    int* s_int = (int*)(ws + off);    off += (size_t)DIMK * sizeof(int);
    off = (off + 255) & ~(size_t)255;
    float* v1 = (float*)(ws + off);   off += (size_t)NROWS * sizeof(float);
    float* u  = (float*)(ws + off);   off += (size_t)NROWS * sizeof(float);
    float* v  = (float*)(ws + off);   off += (size_t)NROWS * sizeof(float);
    off = (off + 255) & ~(size_t)255;
    const size_t kq_bytes = (size_t)NROWS * NROWS;
    const bool use_u8K = (ws_size >= off + kq_bytes);
    unsigned char* Kq = (unsigned char*)(ws + off);

    if (use_u8K) {
        hipMemsetAsync(s_int, 0, DIMK * sizeof(int), stream);
        rownorm_colsum_kernel<<<NROWS / 4, 256, 0, stream>>>(x, Vb, s_int);
        v1_kernel<<<NROWS / 4, 256, 0, stream>>>(Vb, s_int, v1);
        gemm_ku8_kernel<<<528, 256, 0, stream>>>(Vb, Kq);
        finalw_closed_kernel<<<NROWS / 4, 256, 0, stream>>>(Kq, v1, W);
    } else {
        hipMemsetAsync(s_int, 0, DIMK * sizeof(int), stream);
        rownorm_colsum_kernel<<<NROWS / 4, 256, 0, stream>>>(x, Vb, s_int);
        init_u_kernel<<<NROWS / 256, 256, 0, stream>>>(u);
        dim3 ggrid(NROWS / 128, NROWS / 128);
        gemm_k_f32_kernel<<<ggrid, 256, 0, stream>>>(Vb, W);
        for (int it = 0; it < 2; ++it) {
            matvec_f32_kernel<<<NROWS, 256, 0, stream>>>(W, u, v);
            matvec_f32_kernel<<<NROWS, 256, 0, stream>>>(W, v, u);
        }
        finalw_f32_kernel<<<(NROWS * (NROWS / 4)) / 256, 256, 0, stream>>>(W, u, v);
    }
}

// Round 15
// 73.286 us; speedup vs baseline: 1.0771x; 1.0771x over previous
//
#include <hip/hip_runtime.h>
#include <hip/hip_bf16.h>
#include <cstdint>
#include <cstddef>

// Problem constants
#define NROWS 4096
#define DIMK  640
// reg = 1/LAMBDA = 10;  K = exp(-D/reg) = exp(0.2*S - 0.2), S = cosine sim
// K in [exp(-0.4), 1] -> affine uint8 quantization K ~= QA*q + QB
#define QB 0.67032004603564f           /* exp(-0.4) */
#define QA 0.0012928625645661f         /* (1 - exp(-0.4)) / 255 */
// Sinkhorn closed form (verified R8-R14): W = c0*v1_i*v1_j*K_ij, diag=1,
// c0 = 1/sum(v1).  Analytic v1 (verified R11-R14):
//   v1_i = N*e^{0.2} / (C0 + 0.2*t_i),  t_i = v_i . s,  s = V^T 1,
//   C0 = N + 0.02 + 0.02*(N-1)/DIMK - e^{0.2}
#define EXP02 1.2214027581601699f
#define RS_C0 4094.9265661f
#define FIXS  65536.0f
#define FIXSI (1.0f / 65536.0f)

typedef __bf16 bf16_t;
typedef __bf16 bf16x8 __attribute__((ext_vector_type(8)));
typedef float  f32x4  __attribute__((ext_vector_type(4)));

// ---------------------------------------------------------------------------
// A: row-normalize x -> bf16 V + deterministic fixed-point column sums.
// (verified R12-R14)
// ---------------------------------------------------------------------------
__global__ __launch_bounds__(256)
void rownorm_colsum_kernel(const float* __restrict__ x, bf16_t* __restrict__ Vb,
                           int* __restrict__ s_int) {
    __shared__ float P[4][DIMK];
    const int t = threadIdx.x, lane = t & 63, w = t >> 6;
    const int row = blockIdx.x * 4 + w;
    const float* xr = x + (size_t)row * DIMK;
    float xv[10], ss = 0.f;
#pragma unroll
    for (int i = 0; i < 10; ++i) { xv[i] = xr[lane + i * 64]; ss += xv[i] * xv[i]; }
#pragma unroll
    for (int off = 32; off > 0; off >>= 1) ss += __shfl_xor(ss, off, 64);
    const float inv = 1.0f / sqrtf(ss);
    bf16_t* vr = Vb + (size_t)row * DIMK;
#pragma unroll
    for (int i = 0; i < 10; ++i) {
        const float f = xv[i] * inv;
        vr[lane + i * 64] = (bf16_t)f;
        P[w][lane + i * 64] = f;
    }
    __syncthreads();
    for (int k = t; k < DIMK; k += 256)
        atomicAdd(s_int + k,
                  (int)rintf((P[0][k] + P[1][k] + P[2][k] + P[3][k]) * FIXS));
}

// ---------------------------------------------------------------------------
// C: v1_i = N*e^{0.2} / (C0 + 0.2 * (v_i . s)).   (verified R12-R14)
// ---------------------------------------------------------------------------
__global__ __launch_bounds__(256)
void v1_kernel(const bf16_t* __restrict__ Vb, const int* __restrict__ s_int,
               float* __restrict__ v1) {
    const int t = threadIdx.x, lane = t & 63, w = t >> 6;
    const int row = blockIdx.x * 4 + w;
    const uint32_t* vr = (const uint32_t*)(Vb + (size_t)row * DIMK);
    const int2* s2 = (const int2*)s_int;
    float dot = 0.f;
#pragma unroll
    for (int i = 0; i < 5; ++i) {
        const int d = lane + i * 64;
        const uint32_t u = vr[d];
        const int2 sp = s2[d];
        const float f0 = __builtin_bit_cast(float, u << 16);
        const float f1 = __builtin_bit_cast(float, u & 0xffff0000u);
        dot = fmaf(f0, (float)sp.x * FIXSI, dot);
        dot = fmaf(f1, (float)sp.y * FIXSI, dot);
    }
#pragma unroll
    for (int off = 32; off > 0; off >>= 1) dot += __shfl_xor(dot, off, 64);
    if (lane == 0)
        v1[row] = ((float)NROWS * EXP02) / fmaf(0.2f, dot, RS_C0);
}

// ---------------------------------------------------------------------------
// helper: async global->LDS, 16B per lane
// ---------------------------------------------------------------------------
__device__ __forceinline__ void gload_lds16(const bf16_t* g, bf16_t* l) {
    __builtin_amdgcn_global_load_lds(
        (const __attribute__((address_space(1))) void*)g,
        (__attribute__((address_space(3))) void*)l,
        16, 0, 0);
}

// ---------------------------------------------------------------------------
// D: symmetric K-GEMM -> u8.  EXACT R10 structure (proven 30us): 64x128
// half-tiles, 1056 blocks, BK=64, dbuf 48KB (3 blocks/CU), T3 2-phase with
// vmcnt(0)+barrier per step.  R15 changes ONLY:
//  (a) tile enumeration bx-MAJOR + bijective XCD-chunk swizzle (1056=8*132):
//      each XCD runs 66 consecutive prs -> shared B panels (2/3 of read
//      bytes) become L2-resident (T1; pure permutation, no correctness risk)
//  (b) epilogue rowsum atomics removed (v1 analytic).
// ---------------------------------------------------------------------------
__global__ __launch_bounds__(256, 3)
void gemm_ku8_kernel(const bf16_t* __restrict__ Vb, unsigned char* __restrict__ Kq) {
    // dbuf layout (bf16 elems): buf*12288 -> A(4096) | B(8192)
    __shared__ __align__(16) bf16_t SMEM[2 * 12288];   // 48 KB

    const int t    = threadIdx.x;
    const int lane = t & 63;
    const int wid  = t >> 6;
    const int wr   = wid >> 1;       // 0..1 : 32-row band
    const int wc   = wid & 1;        // 0..1 : 64-col band
    const int lane15 = lane & 15;
    const int lhi    = lane >> 4;

    // bijective XCD-chunk swizzle (1056 = 8*132), then bx-major decode:
    // pr enumerated bx-major (for bx: by=0..bx), halves adjacent.
    const int lid  = (blockIdx.x & 7) * 132 + (blockIdx.x >> 3);
    const int half = lid & 1;
    int tt = lid >> 1;               // pr in bx-major order
    int bx = 0;
    while (tt > bx) { tt -= bx + 1; ++bx; }
    const int by = tt;
    const int rowAh = by * 128 + half * 64;   // this block's 64 A-rows
    const int rowB0 = bx * 128;

    f32x4 acc[2][4];
#pragma unroll
    for (int i = 0; i < 2; ++i)
#pragma unroll
        for (int j = 0; j < 4; ++j) acc[i][j] = (f32x4){0.f, 0.f, 0.f, 0.f};

#define STAGE_KT(buf, kt)                                                          \
    {                                                                              \
        bf16_t* Abuf = SMEM + (size_t)(buf) * 12288;                               \
        bf16_t* Bbuf = Abuf + 4096;                                                \
        _Pragma("unroll")                                                          \
        for (int it = 0; it < 2; ++it) {        /* A: 64 rows, 512 chunks */       \
            const int s = it * 256 + t;                                            \
            const int r = s >> 3;                                                  \
            const int c = (s & 7) ^ (r & 7);                                       \
            gload_lds16(Vb + (size_t)(rowAh + r) * DIMK + (kt) * 64 + c * 8,       \
                        Abuf + s * 8);                                             \
        }                                                                          \
        _Pragma("unroll")                                                          \
        for (int it = 0; it < 4; ++it) {        /* B: 128 rows, 1024 chunks */     \
            const int s = it * 256 + t;                                            \
            const int r = s >> 3;                                                  \
            const int c = (s & 7) ^ (r & 7);                                       \
            gload_lds16(Vb + (size_t)(rowB0 + r) * DIMK + (kt) * 64 + c * 8,       \
                        Bbuf + s * 8);                                             \
        }                                                                          \
    }

    STAGE_KT(0, 0);
    __syncthreads();   // drain: buffer 0 ready

    for (int kt = 0; kt < DIMK / 64; ++kt) {
        const int cur = kt & 1;
        if (kt < DIMK / 64 - 1) STAGE_KT(cur ^ 1, kt + 1);   // async prefetch

        const bf16_t* Ac = SMEM + (size_t)cur * 12288;
        const bf16_t* Bc = Ac + 4096;
#pragma unroll
        for (int kk = 0; kk < 2; ++kk) {
            bf16x8 af[2], bfr[4];
            const int cs = kk * 4 + lhi;
#pragma unroll
            for (int mi = 0; mi < 2; ++mi) {
                const int rl = wr * 32 + mi * 16 + lane15;      // 0..63
                af[mi] = *(const bf16x8*)(Ac + rl * 64 + ((cs ^ (rl & 7)) * 8));
            }
#pragma unroll
            for (int ni = 0; ni < 4; ++ni) {
                const int cl = wc * 64 + ni * 16 + lane15;      // 0..127
                bfr[ni] = *(const bf16x8*)(Bc + cl * 64 + ((cs ^ (cl & 7)) * 8));
            }
#pragma unroll
            for (int mi = 0; mi < 2; ++mi)
#pragma unroll
                for (int ni = 0; ni < 4; ++ni)
                    acc[mi][ni] = __builtin_amdgcn_mfma_f32_16x16x32_bf16(
                        af[mi], bfr[ni], acc[mi][ni], 0, 0, 0);
        }

        asm volatile("s_waitcnt vmcnt(0)" ::: "memory");
        __builtin_amdgcn_s_barrier();
        __builtin_amdgcn_sched_barrier(0);
    }
#undef STAGE_KT

    // ---- epilogue (verified R10, minus rowsum atomics): quantize into
    // transposed LDS tile Tt[c][r'] (u8, 8 KB), dword-swizzled.
    uint32_t* Tt32 = (uint32_t*)SMEM;
    unsigned char* Tt = (unsigned char*)SMEM;
    __syncthreads();   // main-loop buffers dead; reuse base
#pragma unroll
    for (int mi = 0; mi < 2; ++mi) {
#pragma unroll
        for (int ni = 0; ni < 4; ++ni) {
            const int lr0 = wr * 32 + mi * 16 + lhi * 4;   // local row base (0..60)
            const int lc  = wc * 64 + ni * 16 + lane15;    // local col (0..127)
            uint32_t pack = 0;
#pragma unroll
            for (int j = 0; j < 4; ++j) {
                const float s = acc[mi][ni][j];
                float kv = __expf(0.2f * s - 0.2f);
                int q = (int)rintf((kv - QB) / QA);
                q = q < 0 ? 0 : (q > 255 ? 255 : q);
                if (rowAh + lr0 + j == rowB0 + lc) q = 0;
                pack |= (uint32_t)q << (8 * j);
            }
            const int d = lr0 >> 2;
            Tt32[lc * 16 + (d ^ ((lc & 7) << 1))] = pack;
        }
    }
    __syncthreads();

    // orientation 1 (always): K[rowB0+c][rowAh + ...], 64B per c-row
    {
        const int c  = t >> 1;        // 0..127
        const int h8 = (t & 1) * 8;   // dword half
        uint32_t w[8];
#pragma unroll
        for (int k = 0; k < 8; ++k) {
            const int d = h8 + k;
            w[k] = Tt32[c * 16 + (d ^ ((c & 7) << 1))];
        }
        uint32_t* dst = (uint32_t*)(Kq + (size_t)(rowB0 + c) * NROWS + rowAh + h8 * 4);
#pragma unroll
        for (int k = 0; k < 2; ++k)
            ((uint4*)dst)[k] = make_uint4(w[4 * k], w[4 * k + 1], w[4 * k + 2], w[4 * k + 3]);
    }

    // orientation 2 (off-diag only): K[rowAh+r][rowB0 + ...], 32B per thread
    if (bx != by) {
        const int r   = t >> 2;        // 0..63
        const int qtr = t & 3;         // 32-col quarter
        const int d0  = r >> 2, b0 = r & 3;
        uint32_t* dst = (uint32_t*)(Kq + (size_t)(rowAh + r) * NROWS + rowB0 + qtr * 32);
#pragma unroll
        for (int k = 0; k < 8; ++k) {
            uint32_t pack = 0;
#pragma unroll
            for (int b = 0; b < 4; ++b) {
                const int c = qtr * 32 + k * 4 + b;
                pack |= (uint32_t)Tt[(c * 16 + (d0 ^ ((c & 7) << 1))) * 4 + b0] << (8 * b);
            }
            dst[k] = pack;
        }
    }
}

// ---------------------------------------------------------------------------
// E: closed-form final W (verified R13/R14):
//   c0 = 1/sum(v1);  W[i][j] = (c0*v1[i]) * (QA*q[i][j] + QB) * v1[j]; diag=1
// ---------------------------------------------------------------------------
__global__ __launch_bounds__(256)
void finalw_closed_kernel(const unsigned char* __restrict__ Kq,
                          const float* __restrict__ v1,
                          float* __restrict__ W) {
    __shared__ float xs[NROWS];
    __shared__ float sxp[4];
    const int t    = threadIdx.x;
    const int lane = t & 63;
    const int w    = t >> 6;

    float psum = 0.f;
    float4* xs4 = (float4*)xs;
    const float4* v4 = (const float4*)v1;
#pragma unroll
    for (int i = 0; i < 4; ++i) {
        const float4 vv = v4[i * 256 + t];
        xs4[i * 256 + t] = vv;
        psum += vv.x + vv.y + vv.z + vv.w;
    }
#pragma unroll
    for (int off = 32; off > 0; off >>= 1) psum += __shfl_xor(psum, off, 64);
    if (lane == 0) sxp[w] = psum;
    __syncthreads();
    const float c0 = 1.0f / (sxp[0] + sxp[1] + sxp[2] + sxp[3]);

#pragma unroll
    for (int r = 0; r < 4; ++r) {
        const int grow = blockIdx.x * 4 + r;
        const float ui   = c0 * xs[grow];
        const float qa_u = QA * ui;
        const float qb_u = QB * ui;
        const uint32_t* Krow = (const uint32_t*)(Kq + (size_t)grow * NROWS);
        f32x4* Wrow = (f32x4*)(W + (size_t)grow * NROWS);
#pragma unroll
        for (int i = 0; i < 4; ++i) {
            const int idx = i * 256 + t;
            const uint32_t q = Krow[idx];
            const float4 vv = ((const float4*)xs4)[idx];
            f32x4 wv;
            wv[0] = fmaf(qa_u, (float)(q & 255u),         qb_u) * vv.x;
            wv[1] = fmaf(qa_u, (float)((q >> 8) & 255u),  qb_u) * vv.y;
            wv[2] = fmaf(qa_u, (float)((q >> 16) & 255u), qb_u) * vv.z;
            wv[3] = fmaf(qa_u, (float)(q >> 24),          qb_u) * vv.w;
            const int d = grow - idx * 4;
            if (d == 0) wv[0] = 1.0f;
            if (d == 1) wv[1] = 1.0f;
            if (d == 2) wv[2] = 1.0f;
            if (d == 3) wv[3] = 1.0f;
            __builtin_nontemporal_store(wv, Wrow + idx);
        }
    }
}

// ---------------------------------------------------------------------------
// f32 fallback path (only if ws too small — never expected): R5 semantics.
// ---------------------------------------------------------------------------
__global__ void init_u_kernel(float* __restrict__ u) {
    const int i = blockIdx.x * 256 + threadIdx.x;
    if (i < NROWS) u[i] = 1.0f / (float)NROWS;
}

__global__ __launch_bounds__(256)
void gemm_k_f32_kernel(const bf16_t* __restrict__ Vb, float* __restrict__ Kout) {
    __shared__ __align__(16) bf16_t As[128 * 64];
    __shared__ __align__(16) bf16_t Bs[128 * 64];
    const int t = threadIdx.x, lane = t & 63, wid = t >> 6;
    const int wr = wid >> 1, wc = wid & 1;
    const int rowA0 = blockIdx.y * 128, rowB0 = blockIdx.x * 128;
    f32x4 acc[4][4];
#pragma unroll
    for (int i = 0; i < 4; ++i)
#pragma unroll
        for (int j = 0; j < 4; ++j) acc[i][j] = (f32x4){0.f, 0.f, 0.f, 0.f};
    for (int kt = 0; kt < DIMK / 64; ++kt) {
#pragma unroll
        for (int it = 0; it < 4; ++it) {
            const int s = it * 256 + t;
            const int r = s >> 3;
            const int c = (s & 7) ^ (r & 7);
            gload_lds16(Vb + (size_t)(rowA0 + r) * DIMK + kt * 64 + c * 8, As + s * 8);
            gload_lds16(Vb + (size_t)(rowB0 + r) * DIMK + kt * 64 + c * 8, Bs + s * 8);
        }
        __syncthreads();
#pragma unroll
        for (int kk = 0; kk < 2; ++kk) {
            bf16x8 af[4], bfr[4];
#pragma unroll
            for (int mi = 0; mi < 4; ++mi) {
                const int rl = wr * 64 + mi * 16 + (lane & 15);
                const int cs = kk * 4 + (lane >> 4);
                af[mi] = *(const bf16x8*)(As + rl * 64 + ((cs ^ (rl & 7)) * 8));
                const int cl = wc * 64 + mi * 16 + (lane & 15);
                bfr[mi] = *(const bf16x8*)(Bs + cl * 64 + ((cs ^ (cl & 7)) * 8));
            }
#pragma unroll
            for (int mi = 0; mi < 4; ++mi)
#pragma unroll
                for (int ni = 0; ni < 4; ++ni)
                    acc[mi][ni] = __builtin_amdgcn_mfma_f32_16x16x32_bf16(
                        af[mi], bfr[ni], acc[mi][ni], 0, 0, 0);
        }
        __syncthreads();
    }
#pragma unroll
    for (int mi = 0; mi < 4; ++mi)
#pragma unroll
        for (int ni = 0; ni < 4; ++ni)
#pragma unroll
            for (int j = 0; j < 4; ++j) {
                const int grow = rowA0 + wr * 64 + mi * 16 + (lane >> 4) * 4 + j;
                const int gcol = rowB0 + wc * 64 + ni * 16 + (lane & 15);
                float kv = __expf(0.2f * acc[mi][ni][j] - 0.2f);
                if (grow == gcol) kv = 0.0f;
                Kout[(size_t)grow * NROWS + gcol] = kv;
            }
}

__global__ void matvec_f32_kernel(const float* __restrict__ K,
                                  const float* __restrict__ x,
                                  float* __restrict__ y) {
    const int row = blockIdx.x, t = threadIdx.x;
    const float4* Kr = (const float4*)(K + (size_t)row * NROWS);
    const float4* xv = (const float4*)x;
    float s = 0.f;
#pragma unroll
    for (int i = 0; i < 4; ++i) {
        const int idx = i * 256 + t;
        const float4 kv = Kr[idx];
        const float4 xw = xv[idx];
        s += kv.x * xw.x + kv.y * xw.y + kv.z * xw.z + kv.w * xw.w;
    }
    for (int off = 32; off > 0; off >>= 1) s += __shfl_down(s, off, 64);
    __shared__ float p[4];
    const int lane = t & 63, wid = t >> 6;
    if (lane == 0) p[wid] = s;
    __syncthreads();
    if (t == 0) y[row] = 1.0f / (p[0] + p[1] + p[2] + p[3]);
}

__global__ void finalw_f32_kernel(float* __restrict__ W,
                                  const float* __restrict__ u,
                                  const float* __restrict__ v) {
    const size_t idx = (size_t)blockIdx.x * 256 + threadIdx.x;
    const size_t base = idx * 4;
    const int i = (int)(base >> 12), j0 = (int)(base & 4095);
    const float ui = u[i];
    float4 kv = ((const float4*)W)[idx];
    const float4 vv = *(const float4*)(v + j0);
    float4 w;
    w.x = ui * kv.x * vv.x;
    w.y = ui * kv.y * vv.y;
    w.z = ui * kv.z * vv.z;
    w.w = ui * kv.w * vv.w;
    const int d = i - j0;
    if (d == 0) w.x = 1.0f;
    if (d == 1) w.y = 1.0f;
    if (d == 2) w.z = 1.0f;
    if (d == 3) w.w = 1.0f;
    ((float4*)W)[idx] = w;
}

// ---------------------------------------------------------------------------
extern "C" void kernel_launch(void* const* d_in, const int* in_sizes, int n_in,
                              void* d_out, int out_size, void* d_ws, size_t ws_size,
                              hipStream_t stream) {
    const float* x = (const float*)d_in[0];
    float* W = (float*)d_out;
    char* ws = (char*)d_ws;

    size_t off = 0;
    bf16_t* Vb = (bf16_t*)(ws + off); off += (size_t)NROWS * DIMK * sizeof(bf16_t);
    int* s_int = (int*)(ws + off);    off += (size_t)DIMK * sizeof(int);
    off = (off + 255) & ~(size_t)255;
    float* v1 = (float*)(ws + off);   off += (size_t)NROWS * sizeof(float);
    float* u  = (float*)(ws + off);   off += (size_t)NROWS * sizeof(float);
    float* v  = (float*)(ws + off);   off += (size_t)NROWS * sizeof(float);
    off = (off + 255) & ~(size_t)255;
    const size_t kq_bytes = (size_t)NROWS * NROWS;
    const bool use_u8K = (ws_size >= off + kq_bytes);
    unsigned char* Kq = (unsigned char*)(ws + off);

    if (use_u8K) {
        hipMemsetAsync(s_int, 0, DIMK * sizeof(int), stream);
        rownorm_colsum_kernel<<<NROWS / 4, 256, 0, stream>>>(x, Vb, s_int);
        v1_kernel<<<NROWS / 4, 256, 0, stream>>>(Vb, s_int, v1);
        gemm_ku8_kernel<<<1056, 256, 0, stream>>>(Vb, Kq);
        finalw_closed_kernel<<<NROWS / 4, 256, 0, stream>>>(Kq, v1, W);
    } else {
        hipMemsetAsync(s_int, 0, DIMK * sizeof(int), stream);
        rownorm_colsum_kernel<<<NROWS / 4, 256, 0, stream>>>(x, Vb, s_int);
        init_u_kernel<<<NROWS / 256, 256, 0, stream>>>(u);
        dim3 ggrid(NROWS / 128, NROWS / 128);
        gemm_k_f32_kernel<<<ggrid, 256, 0, stream>>>(Vb, W);
        for (int it = 0; it < 2; ++it) {
            matvec_f32_kernel<<<NROWS, 256, 0, stream>>>(W, u, v);
            matvec_f32_kernel<<<NROWS, 256, 0, stream>>>(W, v, u);
        }
        finalw_f32_kernel<<<(NROWS * (NROWS / 4)) / 256, 256, 0, stream>>>(W, u, v);
    }
}

// Round 16
// 49.289 us; speedup vs baseline: 1.6015x; 1.4869x over previous
//
#include <hip/hip_runtime.h>
#include <hip/hip_bf16.h>
#include <cstdint>
#include <cstddef>

// Problem constants
#define NROWS 4096
#define DIMK  640
// reg = 1/LAMBDA = 10;  K = exp(-D/reg) = exp(0.2*S - 0.2), S = cosine sim
// K in [exp(-0.4), 1] -> affine uint8 quantization K ~= QA*q + QB
#define QB 0.67032004603564f           /* exp(-0.4) */
#define QA 0.0012928625645661f         /* (1 - exp(-0.4)) / 255 */
// Sinkhorn closed form:  v1_j = N / rowsumK_j ,  u1_i = c0 * v1_i ,
// c0 = 1/sum(v1);  W = c0 * v1_i * v1_j * K_ij , diag = 1.   [verified R8-R10]
// R16 = exact R10 revert.  R13-R15 regressions were the analytic-v1 colsum's
// 640-address atomic hotspot (~20us hidden contention), NOT the GEMM.

typedef __bf16 bf16_t;
typedef __bf16 bf16x8 __attribute__((ext_vector_type(8)));
typedef float  f32x4  __attribute__((ext_vector_type(4)));

__device__ __forceinline__ int bytesum(uint32_t d) {
    return (int)(d & 255u) + (int)((d >> 8) & 255u) +
           (int)((d >> 16) & 255u) + (int)(d >> 24);
}

// ---------------------------------------------------------------------------
// Row-normalize x -> bf16 V; also zeroes rowsum (blocks 0..15).
// ---------------------------------------------------------------------------
__global__ __launch_bounds__(256)
void rownorm_kernel(const float* __restrict__ x, bf16_t* __restrict__ Vb,
                    unsigned int* __restrict__ rowsum) {
    const int t    = threadIdx.x;
    const int lane = t & 63;
    const int w    = t >> 6;
    if (blockIdx.x < 16) rowsum[blockIdx.x * 256 + t] = 0u;
    const int row = blockIdx.x * 4 + w;
    const float* xr = x + (size_t)row * DIMK;
    float xv[10];
    float ss = 0.f;
#pragma unroll
    for (int i = 0; i < 10; ++i) { xv[i] = xr[lane + i * 64]; ss += xv[i] * xv[i]; }
#pragma unroll
    for (int off = 32; off > 0; off >>= 1) ss += __shfl_xor(ss, off, 64);
    const float inv = 1.0f / sqrtf(ss);
    bf16_t* vr = Vb + (size_t)row * DIMK;
#pragma unroll
    for (int i = 0; i < 10; ++i) vr[lane + i * 64] = (bf16_t)(xv[i] * inv);
}

__global__ void init_u_kernel(float* __restrict__ u) {   // fallback path only
    const int i = blockIdx.x * 256 + threadIdx.x;
    if (i < NROWS) u[i] = 1.0f / (float)NROWS;
}

// ---------------------------------------------------------------------------
// helper: async global->LDS, 16B per lane
// ---------------------------------------------------------------------------
__device__ __forceinline__ void gload_lds16(const bf16_t* g, bf16_t* l) {
    __builtin_amdgcn_global_load_lds(
        (const __attribute__((address_space(1))) void*)g,
        (__attribute__((address_space(3))) void*)l,
        16, 0, 0);
}

// ---------------------------------------------------------------------------
// Symmetric K-GEMM (exact R10, proven 49.6us total): 64x128 HALF-tiles
// (1056 blocks), LDS 48KB dbuf (3 blocks/CU), T3 2-phase per K-step.
// Waves: 2x2, each 32 rows x 64 cols (acc[2][4]).
// Epilogue: quantize to u8 (diag 0); stage transposed Tt[c][r'] (128x64 bytes,
// dword-swizzled d^((c&7)<<1)); orientation-1 (always) + orientation-2
// (off-diag) writes + integer rowsum atomics (4096 addrs, ~50 RMW each: cheap).
// ---------------------------------------------------------------------------
__global__ __launch_bounds__(256, 3)
void gemm_k_sym_kernel(const bf16_t* __restrict__ Vb, unsigned char* __restrict__ Kq,
                       unsigned int* __restrict__ rowsum) {
    // dbuf layout (bf16 elems): buf*12288 -> A(4096) | B(8192)
    __shared__ __align__(16) bf16_t SMEM[2 * 12288];   // 48 KB

    const int t    = threadIdx.x;
    const int lane = t & 63;
    const int wid  = t >> 6;
    const int wr   = wid >> 1;       // 0..1 : 32-row band
    const int wc   = wid & 1;        // 0..1 : 64-col band
    const int lane15 = lane & 15;
    const int lhi    = lane >> 4;

    // id decode: off-diag halves first (0..991), diagonal halves last (992..1055)
    int by, bx, half;
    if (blockIdx.x < 992) {
        const int pr = blockIdx.x >> 1;
        half = blockIdx.x & 1;
        int tt = pr;
        by = 0;
        while (tt >= 31 - by) { tt -= 31 - by; ++by; }
        bx = by + 1 + tt;
    } else {
        const int dd = blockIdx.x - 992;
        by = bx = dd >> 1;
        half = dd & 1;
    }
    const int rowAh = by * 128 + half * 64;   // this block's 64 A-rows
    const int rowB0 = bx * 128;

    f32x4 acc[2][4];
#pragma unroll
    for (int i = 0; i < 2; ++i)
#pragma unroll
        for (int j = 0; j < 4; ++j) acc[i][j] = (f32x4){0.f, 0.f, 0.f, 0.f};

#define STAGE_KT(buf, kt)                                                          \
    {                                                                              \
        bf16_t* Abuf = SMEM + (size_t)(buf) * 12288;                               \
        bf16_t* Bbuf = Abuf + 4096;                                                \
        _Pragma("unroll")                                                          \
        for (int it = 0; it < 2; ++it) {        /* A: 64 rows, 512 chunks */       \
            const int s = it * 256 + t;                                            \
            const int r = s >> 3;                                                  \
            const int c = (s & 7) ^ (r & 7);                                       \
            gload_lds16(Vb + (size_t)(rowAh + r) * DIMK + (kt) * 64 + c * 8,       \
                        Abuf + s * 8);                                             \
        }                                                                          \
        _Pragma("unroll")                                                          \
        for (int it = 0; it < 4; ++it) {        /* B: 128 rows, 1024 chunks */     \
            const int s = it * 256 + t;                                            \
            const int r = s >> 3;                                                  \
            const int c = (s & 7) ^ (r & 7);                                       \
            gload_lds16(Vb + (size_t)(rowB0 + r) * DIMK + (kt) * 64 + c * 8,       \
                        Bbuf + s * 8);                                             \
        }                                                                          \
    }

    STAGE_KT(0, 0);
    __syncthreads();   // drain: buffer 0 ready

    for (int kt = 0; kt < DIMK / 64; ++kt) {
        const int cur = kt & 1;
        if (kt < DIMK / 64 - 1) STAGE_KT(cur ^ 1, kt + 1);   // async prefetch

        const bf16_t* Ac = SMEM + (size_t)cur * 12288;
        const bf16_t* Bc = Ac + 4096;
#pragma unroll
        for (int kk = 0; kk < 2; ++kk) {
            bf16x8 af[2], bfr[4];
            const int cs = kk * 4 + lhi;
#pragma unroll
            for (int mi = 0; mi < 2; ++mi) {
                const int rl = wr * 32 + mi * 16 + lane15;      // 0..63
                af[mi] = *(const bf16x8*)(Ac + rl * 64 + ((cs ^ (rl & 7)) * 8));
            }
#pragma unroll
            for (int ni = 0; ni < 4; ++ni) {
                const int cl = wc * 64 + ni * 16 + lane15;      // 0..127
                bfr[ni] = *(const bf16x8*)(Bc + cl * 64 + ((cs ^ (cl & 7)) * 8));
            }
#pragma unroll
            for (int mi = 0; mi < 2; ++mi)
#pragma unroll
                for (int ni = 0; ni < 4; ++ni)
                    acc[mi][ni] = __builtin_amdgcn_mfma_f32_16x16x32_bf16(
                        af[mi], bfr[ni], acc[mi][ni], 0, 0, 0);
        }

        asm volatile("s_waitcnt vmcnt(0)" ::: "memory");
        __builtin_amdgcn_s_barrier();
        __builtin_amdgcn_sched_barrier(0);
    }
#undef STAGE_KT

    // ---- epilogue: quantize into transposed LDS tile Tt[c][r'] (u8, 8 KB)
    // dword d = r'>>2 (0..15), stored at Tt32[c*16 + (d ^ ((c&7)<<1))]
    uint32_t* Tt32 = (uint32_t*)SMEM;
    unsigned char* Tt = (unsigned char*)SMEM;
    __syncthreads();   // main-loop buffers dead; reuse base
#pragma unroll
    for (int mi = 0; mi < 2; ++mi) {
#pragma unroll
        for (int ni = 0; ni < 4; ++ni) {
            const int lr0 = wr * 32 + mi * 16 + lhi * 4;   // local row base (0..60)
            const int lc  = wc * 64 + ni * 16 + lane15;    // local col (0..127)
            uint32_t pack = 0;
#pragma unroll
            for (int j = 0; j < 4; ++j) {
                const float s = acc[mi][ni][j];
                float kv = __expf(0.2f * s - 0.2f);
                int q = (int)rintf((kv - QB) / QA);
                q = q < 0 ? 0 : (q > 255 ? 255 : q);
                if (rowAh + lr0 + j == rowB0 + lc) q = 0;
                pack |= (uint32_t)q << (8 * j);
            }
            const int d = lr0 >> 2;
            Tt32[lc * 16 + (d ^ ((lc & 7) << 1))] = pack;
        }
    }
    __syncthreads();

    // orientation 1 (always): K[rowB0+c][rowAh + ...], 64B per c-row.
    // 2 threads per c-row; + rowsum[rowB0+c] partial (this block's 64 rows).
    {
        const int c  = t >> 1;        // 0..127
        const int h8 = (t & 1) * 8;   // dword half
        uint32_t w[8];
        int bsum = 0;
#pragma unroll
        for (int k = 0; k < 8; ++k) {
            const int d = h8 + k;
            w[k] = Tt32[c * 16 + (d ^ ((c & 7) << 1))];
            bsum += bytesum(w[k]);
        }
        uint32_t* dst = (uint32_t*)(Kq + (size_t)(rowB0 + c) * NROWS + rowAh + h8 * 4);
#pragma unroll
        for (int k = 0; k < 2; ++k)
            ((uint4*)dst)[k] = make_uint4(w[4 * k], w[4 * k + 1], w[4 * k + 2], w[4 * k + 3]);
        bsum += __shfl_xor(bsum, 1, 64);
        if ((t & 1) == 0) atomicAdd(rowsum + rowB0 + c, (unsigned int)bsum);
    }

    // orientation 2 (off-diag only): K[rowAh+r][rowB0 + ...], 32B per thread
    // (4 threads per r-row); + rowsum[rowAh+r] partial (128 cols).
    if (bx != by) {
        const int r   = t >> 2;        // 0..63
        const int qtr = t & 3;         // which 32-col quarter
        const int d0  = r >> 2, b0 = r & 3;
        uint32_t* dst = (uint32_t*)(Kq + (size_t)(rowAh + r) * NROWS + rowB0 + qtr * 32);
        int bsum = 0;
#pragma unroll
        for (int k = 0; k < 8; ++k) {
            uint32_t pack = 0;
#pragma unroll
            for (int b = 0; b < 4; ++b) {
                const int c = qtr * 32 + k * 4 + b;
                pack |= (uint32_t)Tt[(c * 16 + (d0 ^ ((c & 7) << 1))) * 4 + b0] << (8 * b);
            }
            dst[k] = pack;
            bsum += bytesum(pack);
        }
        bsum += __shfl_xor(bsum, 1, 64);
        bsum += __shfl_xor(bsum, 2, 64);
        if (qtr == 0) atomicAdd(rowsum + rowAh + r, (unsigned int)bsum);
    }
}

// ---------------------------------------------------------------------------
// Closed-form final W (verified R8-R10):
//   v1[j] = N / (QA*rowsum[j] + 4095*QB) ; c0 = 1/sum(v1)
//   W[i][j] = (c0*v1[i]) * (QA*q[i][j] + QB) * v1[j] ; diag -> 1
// ---------------------------------------------------------------------------
__global__ __launch_bounds__(256)
void finalw_closed_kernel(const unsigned char* __restrict__ Kq,
                          const unsigned int* __restrict__ rowsum,
                          float* __restrict__ W) {
    __shared__ float xs[NROWS];
    __shared__ float sxp[4];
    const int t    = threadIdx.x;
    const int lane = t & 63;
    const int w    = t >> 6;

    float psum = 0.f;
    float4* xs4 = (float4*)xs;
    const uint4* rs4 = (const uint4*)rowsum;
#pragma unroll
    for (int i = 0; i < 4; ++i) {
        const uint4 rs = rs4[i * 256 + t];
        float4 vv;
        vv.x = (float)NROWS / fmaf(QA, (float)rs.x, 4095.0f * QB);
        vv.y = (float)NROWS / fmaf(QA, (float)rs.y, 4095.0f * QB);
        vv.z = (float)NROWS / fmaf(QA, (float)rs.z, 4095.0f * QB);
        vv.w = (float)NROWS / fmaf(QA, (float)rs.w, 4095.0f * QB);
        xs4[i * 256 + t] = vv;
        psum += vv.x + vv.y + vv.z + vv.w;
    }
#pragma unroll
    for (int off = 32; off > 0; off >>= 1) psum += __shfl_xor(psum, off, 64);
    if (lane == 0) sxp[w] = psum;
    __syncthreads();
    const float c0 = 1.0f / (sxp[0] + sxp[1] + sxp[2] + sxp[3]);

#pragma unroll
    for (int r = 0; r < 4; ++r) {
        const int grow = blockIdx.x * 4 + r;
        const float ui   = c0 * xs[grow];
        const float qa_u = QA * ui;
        const float qb_u = QB * ui;
        const uint32_t* Krow = (const uint32_t*)(Kq + (size_t)grow * NROWS);
        f32x4* Wrow = (f32x4*)(W + (size_t)grow * NROWS);
#pragma unroll
        for (int i = 0; i < 4; ++i) {
            const int idx = i * 256 + t;
            const uint32_t q = Krow[idx];
            const float4 vv = ((const float4*)xs4)[idx];
            f32x4 wv;
            wv[0] = fmaf(qa_u, (float)(q & 255u),         qb_u) * vv.x;
            wv[1] = fmaf(qa_u, (float)((q >> 8) & 255u),  qb_u) * vv.y;
            wv[2] = fmaf(qa_u, (float)((q >> 16) & 255u), qb_u) * vv.z;
            wv[3] = fmaf(qa_u, (float)(q >> 24),          qb_u) * vv.w;
            const int d = grow - idx * 4;
            if (d == 0) wv[0] = 1.0f;
            if (d == 1) wv[1] = 1.0f;
            if (d == 2) wv[2] = 1.0f;
            if (d == 3) wv[3] = 1.0f;
            __builtin_nontemporal_store(wv, Wrow + idx);
        }
    }
}

// ---------------------------------------------------------------------------
// f32 fallback path (only if ws too small for u8 K) — R5 semantics.
// ---------------------------------------------------------------------------
template <typename OUT_T>
__global__ __launch_bounds__(256)
void gemm_k_kernel(const bf16_t* __restrict__ Vb, OUT_T* __restrict__ Kout) {
    __shared__ __align__(16) bf16_t As[128 * 64];
    __shared__ __align__(16) bf16_t Bs[128 * 64];
    const int t    = threadIdx.x;
    const int lane = t & 63;
    const int wid  = t >> 6;
    const int wr   = wid >> 1;
    const int wc   = wid & 1;
    const int rowA0 = blockIdx.y * 128;
    const int rowB0 = blockIdx.x * 128;
    f32x4 acc[4][4];
#pragma unroll
    for (int i = 0; i < 4; ++i)
#pragma unroll
        for (int j = 0; j < 4; ++j) acc[i][j] = (f32x4){0.f, 0.f, 0.f, 0.f};
    for (int kt = 0; kt < DIMK / 64; ++kt) {
#pragma unroll
        for (int it = 0; it < 4; ++it) {
            const int s = it * 256 + t;
            const int r = s >> 3;
            const int c = (s & 7) ^ (r & 7);
            gload_lds16(Vb + (size_t)(rowA0 + r) * DIMK + kt * 64 + c * 8, As + s * 8);
            gload_lds16(Vb + (size_t)(rowB0 + r) * DIMK + kt * 64 + c * 8, Bs + s * 8);
        }
        __syncthreads();
#pragma unroll
        for (int kk = 0; kk < 2; ++kk) {
            bf16x8 af[4], bfr[4];
#pragma unroll
            for (int mi = 0; mi < 4; ++mi) {
                const int rl = wr * 64 + mi * 16 + (lane & 15);
                const int cs = kk * 4 + (lane >> 4);
                af[mi] = *(const bf16x8*)(As + rl * 64 + ((cs ^ (rl & 7)) * 8));
                const int cl = wc * 64 + mi * 16 + (lane & 15);
                bfr[mi] = *(const bf16x8*)(Bs + cl * 64 + ((cs ^ (cl & 7)) * 8));
            }
#pragma unroll
            for (int mi = 0; mi < 4; ++mi)
#pragma unroll
                for (int ni = 0; ni < 4; ++ni)
                    acc[mi][ni] = __builtin_amdgcn_mfma_f32_16x16x32_bf16(
                        af[mi], bfr[ni], acc[mi][ni], 0, 0, 0);
        }
        __syncthreads();
    }
#pragma unroll
    for (int mi = 0; mi < 4; ++mi)
#pragma unroll
        for (int ni = 0; ni < 4; ++ni)
#pragma unroll
            for (int j = 0; j < 4; ++j) {
                const int grow = rowA0 + wr * 64 + mi * 16 + (lane >> 4) * 4 + j;
                const int gcol = rowB0 + wc * 64 + ni * 16 + (lane & 15);
                float kv = __expf(0.2f * acc[mi][ni][j] - 0.2f);
                if (grow == gcol) kv = 0.0f;
                Kout[(size_t)grow * NROWS + gcol] = (OUT_T)kv;
            }
}

__global__ void matvec_f32_kernel(const float* __restrict__ K,
                                  const float* __restrict__ x,
                                  float* __restrict__ y) {
    const int row = blockIdx.x;
    const int t   = threadIdx.x;
    const float4* Kr = (const float4*)(K + (size_t)row * NROWS);
    const float4* xv = (const float4*)x;
    float s = 0.f;
#pragma unroll
    for (int i = 0; i < 4; ++i) {
        const int idx = i * 256 + t;
        const float4 kv = Kr[idx];
        const float4 xw = xv[idx];
        s += kv.x * xw.x + kv.y * xw.y + kv.z * xw.z + kv.w * xw.w;
    }
    for (int off = 32; off > 0; off >>= 1) s += __shfl_down(s, off, 64);
    __shared__ float p[4];
    const int lane = t & 63, wid = t >> 6;
    if (lane == 0) p[wid] = s;
    __syncthreads();
    if (t == 0) y[row] = 1.0f / (p[0] + p[1] + p[2] + p[3]);
}

__global__ void finalw_f32_kernel(float* __restrict__ W,
                                  const float* __restrict__ u,
                                  const float* __restrict__ v) {
    const size_t idx  = (size_t)blockIdx.x * 256 + threadIdx.x;
    const size_t base = idx * 4;
    const int i  = (int)(base >> 12);
    const int j0 = (int)(base & 4095);
    const float ui = u[i];
    float4 kv = ((const float4*)W)[idx];
    const float4 vv = *(const float4*)(v + j0);
    float4 w;
    w.x = ui * kv.x * vv.x;
    w.y = ui * kv.y * vv.y;
    w.z = ui * kv.z * vv.z;
    w.w = ui * kv.w * vv.w;
    const int d = i - j0;
    if (d == 0) w.x = 1.0f;
    if (d == 1) w.y = 1.0f;
    if (d == 2) w.z = 1.0f;
    if (d == 3) w.w = 1.0f;
    ((float4*)W)[idx] = w;
}

// ---------------------------------------------------------------------------
extern "C" void kernel_launch(void* const* d_in, const int* in_sizes, int n_in,
                              void* d_out, int out_size, void* d_ws, size_t ws_size,
                              hipStream_t stream) {
    const float* x = (const float*)d_in[0];
    float* W = (float*)d_out;
    char* ws = (char*)d_ws;

    size_t off = 0;
    bf16_t* Vb = (bf16_t*)(ws + off); off += (size_t)NROWS * DIMK * sizeof(bf16_t);
    unsigned int* rowsum = (unsigned int*)(ws + off); off += (size_t)NROWS * sizeof(unsigned int);
    float*  u  = (float*)(ws + off);  off += (size_t)NROWS * sizeof(float);
    float*  v  = (float*)(ws + off);  off += (size_t)NROWS * sizeof(float);
    off = (off + 255) & ~(size_t)255;
    const size_t kq_bytes = (size_t)NROWS * NROWS;
    const bool use_u8K = (ws_size >= off + kq_bytes);
    unsigned char* Kq = (unsigned char*)(ws + off);

    if (use_u8K) {
        rownorm_kernel<<<NROWS / 4, 256, 0, stream>>>(x, Vb, rowsum);
        gemm_k_sym_kernel<<<1056, 256, 0, stream>>>(Vb, Kq, rowsum);
        finalw_closed_kernel<<<NROWS / 4, 256, 0, stream>>>(Kq, rowsum, W);
    } else {
        rownorm_kernel<<<NROWS / 4, 256, 0, stream>>>(x, Vb, rowsum);
        init_u_kernel<<<NROWS / 256, 256, 0, stream>>>(u);
        dim3 ggrid(NROWS / 128, NROWS / 128);
        gemm_k_kernel<float><<<ggrid, 256, 0, stream>>>(Vb, W);
        for (int it = 0; it < 2; ++it) {
            matvec_f32_kernel<<<NROWS, 256, 0, stream>>>(W, u, v);
            matvec_f32_kernel<<<NROWS, 256, 0, stream>>>(W, v, u);
        }
        finalw_f32_kernel<<<(NROWS * (NROWS / 4)) / 256, 256, 0, stream>>>(W, u, v);
    }
}